// Round 6
// baseline (100.694 us; speedup 1.0000x reference)
//
#include <hip/hip_runtime.h>

#define NQ 10
#define NL 5

typedef float v2f __attribute__((ext_vector_type(2)));

__device__ __forceinline__ v2f sp(float s) { v2f r = { s, s }; return r; }

// ---- cross-lane xor exchange, mask-specialized onto the cheapest pipe ----
// xor 1,2,8: DPP (VALU). xor 16,32: permlane*_swap (VALU, gfx950). xor 4: ds_swizzle.
template <int M>
__device__ __forceinline__ float lane_xor(float v, int lane) {
    unsigned u = __float_as_uint(v);
    if constexpr (M == 1) {        // quad_perm [1,0,3,2]
        return __uint_as_float((unsigned)__builtin_amdgcn_update_dpp(0, (int)u, 0xB1, 0xF, 0xF, true));
    } else if constexpr (M == 2) { // quad_perm [2,3,0,1]
        return __uint_as_float((unsigned)__builtin_amdgcn_update_dpp(0, (int)u, 0x4E, 0xF, 0xF, true));
    } else if constexpr (M == 4) { // ds_swizzle BitMode xor=4
        return __uint_as_float((unsigned)__builtin_amdgcn_ds_swizzle((int)u, 0x101F));
    } else if constexpr (M == 8) { // row_ror:8 == xor8 within 16
        return __uint_as_float((unsigned)__builtin_amdgcn_update_dpp(0, (int)u, 0x128, 0xF, 0xF, true));
    } else if constexpr (M == 16) {
#if __has_builtin(__builtin_amdgcn_permlane16_swap)
        auto r = __builtin_amdgcn_permlane16_swap(u, u, false, false);
        return __uint_as_float((lane & 16) ? r[0] : r[1]);
#else
        return __uint_as_float((unsigned)__builtin_amdgcn_ds_swizzle((int)u, 0x401F));
#endif
    } else {
#if __has_builtin(__builtin_amdgcn_permlane32_swap)
        auto r = __builtin_amdgcn_permlane32_swap(u, u, false, false);
        return __uint_as_float((lane & 32) ? r[0] : r[1]);
#else
        return __shfl_xor(v, 32, 64);
#endif
    }
}

// U = Rz(tz) @ Ry(ty) @ Rx(tx)  (SU(2): u11 = conj(u00), u10 = -conj(u01))
__device__ __forceinline__ void make_u(float tx, float ty, float tz,
                                       float& u00r, float& u00i, float& u01r, float& u01i,
                                       float& u10r, float& u10i, float& u11r, float& u11i) {
    float cx, sx, cy, sy, cz, sz;
    __sincosf(0.5f * tx, &sx, &cx);
    __sincosf(0.5f * ty, &sy, &cy);
    __sincosf(0.5f * tz, &sz, &cz);
    u00r =  cz * cy * cx + sz * sy * sx;
    u00i =  cz * sy * sx - sz * cy * cx;
    u01r = -cz * sy * cx - sz * cy * sx;
    u01i =  sz * sy * cx - cz * cy * sx;
    u10r = -u01r;  u10i =  u01i;
    u11r =  u00r;  u11i = -u00i;
}

// Setup: 60 gate matrices. gm[g*16+0..7] = V0 = U ; gm[g*16+8..15] = V1 = -i*U*X.
__global__ void pqc_setup(const float* __restrict__ theta, float* __restrict__ gm) {
    int g = threadIdx.x;
    if (g >= (NL + 1) * NQ) return;
    const float* th = theta + g * 3;
    float u00r, u00i, u01r, u01i, u10r, u10i, u11r, u11i;
    make_u(th[0], th[1], th[2], u00r, u00i, u01r, u01i, u10r, u10i, u11r, u11i);
    float* o = gm + g * 16;
    o[0] = u00r;  o[1] = u00i;  o[2] = u01r;  o[3] = u01i;
    o[4] = u10r;  o[5] = u10i;  o[6] = u11r;  o[7] = u11i;
    o[8]  = u01i; o[9]  = -u01r; o[10] = u00i; o[11] = -u00r;
    o[12] = u11i; o[13] = -u11r; o[14] = u10i; o[15] = -u10r;
}

// State: element split across 2 waves. Amplitude k = (h<<9) | (lane<<3) | (2j+e).
// fr[j]/fi[j] (j=0..3) hold re/im of r = 2j, 2j+1.
// Bit P of k: P=0 -> e (in v2f), P=1,2 -> j bits, P=3..8 -> lane bits, P=9 -> wave half.
template <int P>
__device__ __forceinline__ void apply_p(v2f fr[4], v2f fi[4],
                                        float w00r, float w00i, float w01r, float w01i,
                                        float w10r, float w10i, float w11r, float w11i,
                                        int lane) {
    if constexpr (P == 0) {
        v2f c0r = { w00r, w11r }, c0i = { w00i, w11i };
        v2f c1r = { w01r, w10r }, c1i = { w01i, w10i };
#pragma unroll
        for (int j = 0; j < 4; ++j) {
            v2f ar = fr[j], ai = fi[j];
            v2f srp = ar.yx, sip = ai.yx;
            fr[j] = c0r * ar - c0i * ai + c1r * srp - c1i * sip;
            fi[j] = c0r * ai + c0i * ar + c1r * sip + c1i * srp;
        }
    } else if constexpr (P < 3) {
        constexpr int LJ = 1 << (P - 1);
        v2f a00r = sp(w00r), a00i = sp(w00i), a01r = sp(w01r), a01i = sp(w01i);
        v2f a10r = sp(w10r), a10i = sp(w10i), a11r = sp(w11r), a11i = sp(w11i);
#pragma unroll
        for (int base = 0; base < 4; ++base) {
            if (base & LJ) continue;
            v2f a0r = fr[base], a0i = fi[base];
            v2f a1r = fr[base | LJ], a1i = fi[base | LJ];
            fr[base]      = a00r * a0r - a00i * a0i + a01r * a1r - a01i * a1i;
            fi[base]      = a00r * a0i + a00i * a0r + a01r * a1i + a01i * a1r;
            fr[base | LJ] = a10r * a0r - a10i * a0i + a11r * a1r - a11i * a1i;
            fi[base | LJ] = a10r * a0i + a10i * a0r + a11r * a1i + a11i * a1r;
        }
    } else {
        constexpr int M = 1 << (P - 3);
        const int bit = (lane >> (P - 3)) & 1;
        v2f pr = sp(bit ? w11r : w00r), pi = sp(bit ? w11i : w00i);
        v2f qr = sp(bit ? w10r : w01r), qi = sp(bit ? w10i : w01i);
#pragma unroll
        for (int j = 0; j < 4; ++j) {
            v2f ofr, ofi;
            ofr.x = lane_xor<M>(fr[j].x, lane);
            ofr.y = lane_xor<M>(fr[j].y, lane);
            ofi.x = lane_xor<M>(fi[j].x, lane);
            ofi.y = lane_xor<M>(fi[j].y, lane);
            v2f nr = pr * fr[j] - pi * fi[j] + qr * ofr - qi * ofi;
            v2f ni = pr * fi[j] + pi * fr[j] + qr * ofi + qi * ofr;
            fr[j] = nr;
            fi[j] = ni;
        }
    }
}

// Bit-9 gate: exchange with the partner wave through LDS (double-buffered; one barrier).
// Layout (dword units): slot*256 + h*128 + lane*2, slots 0-3 = fr, 4-7 = fi. 8B-aligned.
__device__ __forceinline__ void apply_p9(v2f fr[4], v2f fi[4],
                                         float w00r, float w00i, float w01r, float w01i,
                                         float w10r, float w10i, float w11r, float w11i,
                                         int h, int lane, float* buf) {
    float* mine = buf + h * 128 + lane * 2;
#pragma unroll
    for (int j = 0; j < 4; ++j) {
        *(v2f*)(mine + j * 256)       = fr[j];
        *(v2f*)(mine + (4 + j) * 256) = fi[j];
    }
    __syncthreads();
    const float* part = buf + (1 - h) * 128 + lane * 2;
    v2f pr = sp(h ? w11r : w00r), pi = sp(h ? w11i : w00i);
    v2f qr = sp(h ? w10r : w01r), qi = sp(h ? w10i : w01i);
#pragma unroll
    for (int j = 0; j < 4; ++j) {
        v2f ofr = *(const v2f*)(part + j * 256);
        v2f ofi = *(const v2f*)(part + (4 + j) * 256);
        v2f nr = pr * fr[j] - pi * fi[j] + qr * ofr - qi * ofi;
        v2f ni = pr * fi[j] + pi * fr[j] + qr * ofi + qi * ofr;
        fr[j] = nr;
        fi[j] = ni;
    }
}

// wire q (1..9) -> bit position 9-q (8..0). wire 0 handled by apply_p9.
__device__ __forceinline__ void apply_q(v2f fr[4], v2f fi[4],
                                        float w00r, float w00i, float w01r, float w01i,
                                        float w10r, float w10i, float w11r, float w11i,
                                        int q, int lane) {
    switch (q) {
        case 1: apply_p<8>(fr, fi, w00r, w00i, w01r, w01i, w10r, w10i, w11r, w11i, lane); break;
        case 2: apply_p<7>(fr, fi, w00r, w00i, w01r, w01i, w10r, w10i, w11r, w11i, lane); break;
        case 3: apply_p<6>(fr, fi, w00r, w00i, w01r, w01i, w10r, w10i, w11r, w11i, lane); break;
        case 4: apply_p<5>(fr, fi, w00r, w00i, w01r, w01i, w10r, w10i, w11r, w11i, lane); break;
        case 5: apply_p<4>(fr, fi, w00r, w00i, w01r, w01i, w10r, w10i, w11r, w11i, lane); break;
        case 6: apply_p<3>(fr, fi, w00r, w00i, w01r, w01i, w10r, w10i, w11r, w11i, lane); break;
        case 7: apply_p<2>(fr, fi, w00r, w00i, w01r, w01i, w10r, w10i, w11r, w11i, lane); break;
        case 8: apply_p<1>(fr, fi, w00r, w00i, w01r, w01i, w10r, w10i, w11r, w11i, lane); break;
        case 9: apply_p<0>(fr, fi, w00r, w00i, w01r, w01i, w10r, w10i, w11r, w11i, lane); break;
    }
}

__global__ void __launch_bounds__(128) pqc_kernel(const float* __restrict__ x,
                                                  const float* __restrict__ lam,
                                                  const float* __restrict__ w,
                                                  const float* __restrict__ gm,
                                                  float* __restrict__ out, int B) {
    __shared__ float lds[2][2048];
    const int lane = threadIdx.x & 63;
    const int h = threadIdx.x >> 6;            // amplitude bit 9
    const int b = blockIdx.x;                  // grid.x == B exactly

    v2f fr[4], fi[4];
#pragma unroll
    for (int j = 0; j < 4; ++j) { fr[j] = sp(0.f); fi[j] = sp(0.f); }
    if (h == 0 && lane == 0) fr[0].x = 1.f;

    // CZ-ring sign vectors and Z^n parity mask for this thread's 8 amplitudes.
    v2f sv[4];
    unsigned zmask = 0;
#pragma unroll
    for (int j = 0; j < 4; ++j) {
#pragma unroll
        for (int e = 0; e < 2; ++e) {
            int k = (h << 9) | (lane << 3) | (2 * j + e);
            int par = (__popc(k & (k >> 1)) + ((k & (k >> 9)) & 1)) & 1;
            float s = __uint_as_float(0x3f800000u | ((unsigned)par << 31));
            if (e == 0) sv[j].x = s; else sv[j].y = s;
            zmask |= (unsigned)(__popc(k) & 1) << (2 * j + e);
        }
    }

    float xr[NQ];
#pragma unroll
    for (int q = 0; q < NQ; ++q) xr[q] = x[b * NQ + q];

    // Layer 0: variational gates straight from V0. Wire 0 first (LDS exchange, buf 0).
    {
        const float* g = gm;
        apply_p9(fr, fi, g[0], g[1], g[2], g[3], g[4], g[5], g[6], g[7], h, lane, lds[0]);
#pragma unroll
        for (int q = 1; q < NQ; ++q) {
            const float* gq = gm + q * 16;
            apply_q(fr, fi, gq[0], gq[1], gq[2], gq[3], gq[4], gq[5], gq[6], gq[7], q, lane);
        }
#pragma unroll
        for (int j = 0; j < 4; ++j) { fr[j] *= sv[j]; fi[j] *= sv[j]; }
    }

    // Layers 1..NL: W = c*V0 + s*V1 (fused U_theta * RX(x*lam)), wire 0 via LDS (buf l&1).
#pragma unroll
    for (int l = 1; l <= NL; ++l) {
        const float* lm = lam + (l - 1) * NQ;
#pragma unroll
        for (int q = 0; q < NQ; ++q) {
            const float* g = gm + (l * NQ + q) * 16;
            float t = xr[q] * lm[q];
            float c, s;
            __sincosf(0.5f * t, &s, &c);
            float w00r = c * g[0] + s * g[8],  w00i = c * g[1] + s * g[9];
            float w01r = c * g[2] + s * g[10], w01i = c * g[3] + s * g[11];
            float w10r = c * g[4] + s * g[12], w10i = c * g[5] + s * g[13];
            float w11r = c * g[6] + s * g[14], w11i = c * g[7] + s * g[15];
            if (q == 0)
                apply_p9(fr, fi, w00r, w00i, w01r, w01i, w10r, w10i, w11r, w11i, h, lane, lds[l & 1]);
            else
                apply_q(fr, fi, w00r, w00i, w01r, w01i, w10r, w10i, w11r, w11i, q, lane);
        }
#pragma unroll
        for (int j = 0; j < 4; ++j) { fr[j] *= sv[j]; fi[j] *= sv[j]; }
    }

    // <Z^n> partial over this wave's 512 amplitudes.
    v2f acc = sp(0.f);
#pragma unroll
    for (int j = 0; j < 4; ++j) {
        v2f zs;
        zs.x = __uint_as_float(0x3f800000u | (((zmask >> (2 * j)) & 1u) << 31));
        zs.y = __uint_as_float(0x3f800000u | (((zmask >> (2 * j + 1)) & 1u) << 31));
        acc += zs * (fr[j] * fr[j] + fi[j] * fi[j]);
    }
    float ez = acc.x + acc.y;
    ez += lane_xor<1>(ez, lane);
    ez += lane_xor<2>(ez, lane);
    ez += lane_xor<4>(ez, lane);
    ez += lane_xor<8>(ez, lane);
    ez += lane_xor<16>(ez, lane);
    ez += lane_xor<32>(ez, lane);

    // Combine the two wave halves and emit softmax.
    if (lane == 0) lds[0][h] = ez;
    __syncthreads();
    if (h == 0 && lane == 0) {
        float e = lds[0][0] + lds[0][1];
        float l0 = e * w[0], l1 = e * w[1];    // BETA = 1
        float m = fmaxf(l0, l1);
        float e0 = __expf(l0 - m), e1 = __expf(l1 - m);
        float inv = 1.f / (e0 + e1);
        out[2 * b + 0] = e0 * inv;
        out[2 * b + 1] = e1 * inv;
    }
}

extern "C" void kernel_launch(void* const* d_in, const int* in_sizes, int n_in,
                              void* d_out, int out_size, void* d_ws, size_t ws_size,
                              hipStream_t stream) {
    const float* x     = (const float*)d_in[0];
    const float* theta = (const float*)d_in[1];
    const float* lam   = (const float*)d_in[2];
    const float* w     = (const float*)d_in[3];
    float* out = (float*)d_out;
    float* gm  = (float*)d_ws;                 // 60 gates * 16 floats = 3840 B

    const int B = in_sizes[0] / NQ;            // 2048
    hipLaunchKernelGGL(pqc_setup, dim3(1), dim3(64), 0, stream, theta, gm);
    hipLaunchKernelGGL(pqc_kernel, dim3(B), dim3(128), 0, stream,
                       x, lam, w, gm, out, B);
}

// Round 7
// 90.264 us; speedup vs baseline: 1.1155x; 1.1155x over previous
//
#include <hip/hip_runtime.h>

#define NQ 10
#define NL 5

typedef float v2f __attribute__((ext_vector_type(2)));

__device__ __forceinline__ v2f sp(float s) { v2f r = { s, s }; return r; }

// ---- cross-lane xor exchange, mask-specialized onto the cheapest pipe ----
// xor 1,2,8: DPP (VALU). xor 16,32: permlane*_swap (VALU, gfx950). xor 4: ds_swizzle.
template <int M>
__device__ __forceinline__ float lane_xor(float v, int lane) {
    unsigned u = __float_as_uint(v);
    if constexpr (M == 1) {        // quad_perm [1,0,3,2]
        return __uint_as_float((unsigned)__builtin_amdgcn_update_dpp(0, (int)u, 0xB1, 0xF, 0xF, true));
    } else if constexpr (M == 2) { // quad_perm [2,3,0,1]
        return __uint_as_float((unsigned)__builtin_amdgcn_update_dpp(0, (int)u, 0x4E, 0xF, 0xF, true));
    } else if constexpr (M == 4) { // ds_swizzle BitMode xor=4
        return __uint_as_float((unsigned)__builtin_amdgcn_ds_swizzle((int)u, 0x101F));
    } else if constexpr (M == 8) { // row_ror:8 == xor8 within 16
        return __uint_as_float((unsigned)__builtin_amdgcn_update_dpp(0, (int)u, 0x128, 0xF, 0xF, true));
    } else if constexpr (M == 16) {
#if __has_builtin(__builtin_amdgcn_permlane16_swap)
        auto r = __builtin_amdgcn_permlane16_swap(u, u, false, false);
        return __uint_as_float((lane & 16) ? r[0] : r[1]);
#else
        return __uint_as_float((unsigned)__builtin_amdgcn_ds_swizzle((int)u, 0x401F));
#endif
    } else {
#if __has_builtin(__builtin_amdgcn_permlane32_swap)
        auto r = __builtin_amdgcn_permlane32_swap(u, u, false, false);
        return __uint_as_float((lane & 32) ? r[0] : r[1]);
#else
        return __shfl_xor(v, 32, 64);
#endif
    }
}

// U = Rz(tz) @ Ry(ty) @ Rx(tx)  (SU(2): u11 = conj(u00), u10 = -conj(u01))
__device__ __forceinline__ void make_u(float tx, float ty, float tz,
                                       float& u00r, float& u00i, float& u01r, float& u01i,
                                       float& u10r, float& u10i, float& u11r, float& u11i) {
    float cx, sx, cy, sy, cz, sz;
    __sincosf(0.5f * tx, &sx, &cx);
    __sincosf(0.5f * ty, &sy, &cy);
    __sincosf(0.5f * tz, &sz, &cz);
    u00r =  cz * cy * cx + sz * sy * sx;
    u00i =  cz * sy * sx - sz * cy * cx;
    u01r = -cz * sy * cx - sz * cy * sx;
    u01i =  sz * sy * cx - cz * cy * sx;
    u10r = -u01r;  u10i =  u01i;
    u11r =  u00r;  u11i = -u00i;
}

// Setup: 60 gate matrices. gm[g*16+0..7] = V0 = U ; gm[g*16+8..15] = V1 = -i*U*X.
__global__ void pqc_setup(const float* __restrict__ theta, float* __restrict__ gm) {
    int g = threadIdx.x;
    if (g >= (NL + 1) * NQ) return;
    const float* th = theta + g * 3;
    float u00r, u00i, u01r, u01i, u10r, u10i, u11r, u11i;
    make_u(th[0], th[1], th[2], u00r, u00i, u01r, u01i, u10r, u10i, u11r, u11i);
    float* o = gm + g * 16;
    o[0] = u00r;  o[1] = u00i;  o[2] = u01r;  o[3] = u01i;
    o[4] = u10r;  o[5] = u10i;  o[6] = u11r;  o[7] = u11i;
    o[8]  = u01i; o[9]  = -u01r; o[10] = u00i; o[11] = -u00r;
    o[12] = u11i; o[13] = -u11r; o[14] = u10i; o[15] = -u10r;
}

// State: amplitude k = lane*16 + r, r = 2*j + h.  fr[j]/fi[j] hold re/im of (r=2j, r=2j+1).
// Bit P of k: P=0 -> h (in v2f), P=1..3 -> j bits, P=4..9 -> lane bits.
template <int P>
__device__ __forceinline__ void apply_p(v2f fr[8], v2f fi[8], const float wv[8], int lane) {
    const float w00r = wv[0], w00i = wv[1], w01r = wv[2], w01i = wv[3];
    const float w10r = wv[4], w10i = wv[5], w11r = wv[6], w11i = wv[7];
    if constexpr (P == 0) {
        v2f c0r = { w00r, w11r }, c0i = { w00i, w11i };
        v2f c1r = { w01r, w10r }, c1i = { w01i, w10i };
#pragma unroll
        for (int j = 0; j < 8; ++j) {
            v2f ar = fr[j], ai = fi[j];
            v2f srp = ar.yx, sip = ai.yx;
            fr[j] = c0r * ar - c0i * ai + c1r * srp - c1i * sip;
            fi[j] = c0r * ai + c0i * ar + c1r * sip + c1i * srp;
        }
    } else if constexpr (P < 4) {
        constexpr int LJ = 1 << (P - 1);
        v2f a00r = sp(w00r), a00i = sp(w00i), a01r = sp(w01r), a01i = sp(w01i);
        v2f a10r = sp(w10r), a10i = sp(w10i), a11r = sp(w11r), a11i = sp(w11i);
#pragma unroll
        for (int base = 0; base < 8; ++base) {
            if (base & LJ) continue;
            v2f a0r = fr[base], a0i = fi[base];
            v2f a1r = fr[base | LJ], a1i = fi[base | LJ];
            fr[base]      = a00r * a0r - a00i * a0i + a01r * a1r - a01i * a1i;
            fi[base]      = a00r * a0i + a00i * a0r + a01r * a1i + a01i * a1r;
            fr[base | LJ] = a10r * a0r - a10i * a0i + a11r * a1r - a11i * a1i;
            fi[base | LJ] = a10r * a0i + a10i * a0r + a11r * a1i + a11i * a1r;
        }
    } else {
        constexpr int M = 1 << (P - 4);
        const int bit = (lane >> (P - 4)) & 1;
        v2f pr = sp(bit ? w11r : w00r), pi = sp(bit ? w11i : w00i);
        v2f qr = sp(bit ? w10r : w01r), qi = sp(bit ? w10i : w01i);
#pragma unroll
        for (int j = 0; j < 8; ++j) {
            v2f ofr, ofi;
            ofr.x = lane_xor<M>(fr[j].x, lane);
            ofr.y = lane_xor<M>(fr[j].y, lane);
            ofi.x = lane_xor<M>(fi[j].x, lane);
            ofi.y = lane_xor<M>(fi[j].y, lane);
            v2f nr = pr * fr[j] - pi * fi[j] + qr * ofr - qi * ofi;
            v2f ni = pr * fi[j] + pi * fr[j] + qr * ofi + qi * ofr;
            fr[j] = nr;
            fi[j] = ni;
        }
    }
}

// Apply a full layer: wire q hits bit 9-q; wires 0..9 in order, then CZ signs.
__device__ __forceinline__ void apply_layer(v2f fr[8], v2f fi[8], const float W[NQ][8],
                                            const v2f sv[8], int lane) {
    apply_p<9>(fr, fi, W[0], lane);
    apply_p<8>(fr, fi, W[1], lane);
    apply_p<7>(fr, fi, W[2], lane);
    apply_p<6>(fr, fi, W[3], lane);
    apply_p<5>(fr, fi, W[4], lane);
    apply_p<4>(fr, fi, W[5], lane);
    apply_p<3>(fr, fi, W[6], lane);
    apply_p<2>(fr, fi, W[7], lane);
    apply_p<1>(fr, fi, W[8], lane);
    apply_p<0>(fr, fi, W[9], lane);
#pragma unroll
    for (int j = 0; j < 8; ++j) { fr[j] *= sv[j]; fi[j] *= sv[j]; }
}

// block = 64 (one wave, one batch element); min 2 waves/EU -> VGPR cap 256:
// grid is only 2048 waves (2/SIMD), so registers up to 256 are free — spend them on ILP.
__global__ void __launch_bounds__(64, 2) pqc_kernel(const float* __restrict__ x,
                                                    const float* __restrict__ lam,
                                                    const float* __restrict__ w,
                                                    const float* __restrict__ gm,
                                                    float* __restrict__ out, int B) {
    const int lane = threadIdx.x;
    const int b = blockIdx.x;

    v2f fr[8], fi[8];
#pragma unroll
    for (int j = 0; j < 8; ++j) { fr[j] = sp(0.f); fi[j] = sp(0.f); }
    if (lane == 0) fr[0].x = 1.f;

    // CZ-ring sign vectors and Z^n parity mask for this lane's 16 amplitudes.
    v2f sv[8];
    unsigned zmask = 0;
#pragma unroll
    for (int j = 0; j < 8; ++j) {
#pragma unroll
        for (int h = 0; h < 2; ++h) {
            int k = (lane << 4) | (2 * j + h);
            int par = (__popc(k & (k >> 1)) + ((k & (k >> 9)) & 1)) & 1;
            float s = __uint_as_float(0x3f800000u | ((unsigned)par << 31));
            if (h == 0) sv[j].x = s; else sv[j].y = s;
            zmask |= (unsigned)(__popc(k) & 1) << (2 * j + h);
        }
    }

    float xr[NQ];
#pragma unroll
    for (int q = 0; q < NQ; ++q) xr[q] = x[b * NQ + q];

    // Layer 0: W = V0 straight from gm (wave-uniform s_loads).
    {
        float W[NQ][8];
#pragma unroll
        for (int q = 0; q < NQ; ++q)
#pragma unroll
            for (int t = 0; t < 8; ++t) W[q][t] = gm[q * 16 + t];
        apply_layer(fr, fi, W, sv, lane);
    }

    // Layers 1..NL: all 10 sincos (independent), then all 10 W = c*V0 + s*V1, then apply.
#pragma unroll
    for (int l = 1; l <= NL; ++l) {
        const float* lm = lam + (l - 1) * NQ;
        float cc[NQ], ss[NQ];
#pragma unroll
        for (int q = 0; q < NQ; ++q)
            __sincosf(0.5f * xr[q] * lm[q], &ss[q], &cc[q]);
        float W[NQ][8];
#pragma unroll
        for (int q = 0; q < NQ; ++q) {
            const float* g = gm + (l * NQ + q) * 16;
#pragma unroll
            for (int t = 0; t < 8; ++t) W[q][t] = cc[q] * g[t] + ss[q] * g[8 + t];
        }
        apply_layer(fr, fi, W, sv, lane);
    }

    // <Z^n> = sum |amp|^2 * (-1)^popcount(k)
    v2f acc = sp(0.f);
#pragma unroll
    for (int j = 0; j < 8; ++j) {
        v2f zs;
        zs.x = __uint_as_float(0x3f800000u | (((zmask >> (2 * j)) & 1u) << 31));
        zs.y = __uint_as_float(0x3f800000u | (((zmask >> (2 * j + 1)) & 1u) << 31));
        acc += zs * (fr[j] * fr[j] + fi[j] * fi[j]);
    }
    float ez = acc.x + acc.y;
    ez += lane_xor<1>(ez, lane);
    ez += lane_xor<2>(ez, lane);
    ez += lane_xor<4>(ez, lane);
    ez += lane_xor<8>(ez, lane);
    ez += lane_xor<16>(ez, lane);
    ez += lane_xor<32>(ez, lane);

    if (lane == 0) {
        float l0 = ez * w[0], l1 = ez * w[1];   // BETA = 1
        float m = fmaxf(l0, l1);
        float e0 = __expf(l0 - m), e1 = __expf(l1 - m);
        float inv = 1.f / (e0 + e1);
        out[2 * b + 0] = e0 * inv;
        out[2 * b + 1] = e1 * inv;
    }
}

extern "C" void kernel_launch(void* const* d_in, const int* in_sizes, int n_in,
                              void* d_out, int out_size, void* d_ws, size_t ws_size,
                              hipStream_t stream) {
    const float* x     = (const float*)d_in[0];
    const float* theta = (const float*)d_in[1];
    const float* lam   = (const float*)d_in[2];
    const float* w     = (const float*)d_in[3];
    float* out = (float*)d_out;
    float* gm  = (float*)d_ws;                 // 60 gates * 16 floats = 3840 B

    const int B = in_sizes[0] / NQ;            // 2048
    hipLaunchKernelGGL(pqc_setup, dim3(1), dim3(64), 0, stream, theta, gm);
    hipLaunchKernelGGL(pqc_kernel, dim3(B), dim3(64), 0, stream,
                       x, lam, w, gm, out, B);
}